// Round 7
// baseline (365.853 us; speedup 1.0000x reference)
//
#include <hip/hip_runtime.h>
#include <stdint.h>

// BCM_Linear: out = x @ W^T, W[o,k] = w[o>>6, k>>6, (o-k)&63]  (1024x1024)
// M=32768, N=1024, K=1024. bf16 MFMA compute, fp32 in/out.
// Round 7: fused A-conversion (distance-2 reg prefetch -> cvt -> swizzled
// ds_write), B fragments loaded DIRECTLY global->reg (L2-resident Wb, 2 banks,
// distance-1). No global_load_lds, no manual vmcnt: all global-load waits are
// compiler-inserted (correct by construction). LDS = A only (32 KB).
// 128x128 tile, 512 threads, 2 blocks/CU.

#define NTOK 32768
#define NCH  1024
#define BK   64
#define NKT  (NCH / BK)   // 16

typedef short bf16x8 __attribute__((ext_vector_type(8)));
typedef float f32x4  __attribute__((ext_vector_type(4)));
typedef unsigned short u16x8 __attribute__((ext_vector_type(8)));

static __device__ __forceinline__ unsigned short f2bf(float f) {
    unsigned int u = __float_as_uint(f);
    u += 0x7FFFu + ((u >> 16) & 1u);
    return (unsigned short)(u >> 16);
}

static __device__ __forceinline__ u16x8 pack8(float4 a, float4 b) {
    u16x8 v;
    v[0]=f2bf(a.x); v[1]=f2bf(a.y); v[2]=f2bf(a.z); v[3]=f2bf(a.w);
    v[4]=f2bf(b.x); v[5]=f2bf(b.y); v[6]=f2bf(b.z); v[7]=f2bf(b.w);
    return v;
}

// ---------------- kernel 1: circulant w -> dense bf16 W (N x K), UNSWIZZLED ----------------
__global__ void build_w_kernel(const float* __restrict__ w, unsigned short* __restrict__ Wb) {
    int i = blockIdx.x * blockDim.x + threadIdx.x;   // 0 .. 1024*128-1
    int o = i >> 7;
    int j = i & 127;                 // 8-element chunk within row
    int r = o >> 6;
    int q = j >> 3;
    const float* wrow = w + ((r * 16 + q) << 6);
    int k0 = j << 3;
    u16x8 v;
#pragma unroll
    for (int e = 0; e < 8; ++e) v[e] = f2bf(wrow[(o - (k0 + e)) & 63]);
    *(u16x8*)(Wb + (((size_t)o) << 10) + (j << 3)) = v;
}

// ---------------- kernel 2: 128x128 fused GEMM, reg-B ----------------
#define PHASE_BAR() __builtin_amdgcn_s_barrier()
#define LGKM0() asm volatile("s_waitcnt lgkmcnt(0)" ::: "memory")
#define CFENCE() asm volatile("" ::: "memory")
#define SETPRIO(n) __builtin_amdgcn_s_setprio(n)
#define MFMA4(d, av, bv) d = __builtin_amdgcn_mfma_f32_16x16x32_bf16(av, bv, d, 0, 0, 0)
#define NOHOOK ((void)0)

// A issue into named bank: 16 consecutive fp32 of row tid>>2, cols (tid&3)*16 + t*64.
#define ISSUE_A(bank, t) do {                                                    \
    const float4* _p = (const float4*)(pA + ((t) << 6));                         \
    bank[0] = _p[0]; bank[1] = _p[1]; bank[2] = _p[2]; bank[3] = _p[3];          \
} while (0)

// B issue into named bank: 4x 16B direct global loads (L1/L2-resident Wb).
// bank[n][ks] = Wb[row = n0 + wc*32 + n*16 + (lane&15)][k = t*64 + ks*32 + (lane>>4)*8 ..+8]
#define ISSUE_B(bank, t) do {                                                    \
    const char* _b = pB + ((t) << 7);                                            \
    bank[0][0] = *(const bf16x8*)(_b);                                           \
    bank[0][1] = *(const bf16x8*)(_b + 64);                                      \
    bank[1][0] = *(const bf16x8*)(_b + 32768);                                   \
    bank[1][1] = *(const bf16x8*)(_b + 32768 + 64);                              \
} while (0)

// A write from bank: cvt 16 floats -> 2 swizzled ds_write_b128 (proven pattern).
#define WRITE_A(bank, Abuf) do {                                                 \
    u16x8 _w0 = pack8(bank[0], bank[1]);                                         \
    u16x8 _w1 = pack8(bank[2], bank[3]);                                         \
    *(u16x8*)((Abuf) + aw0) = _w0;                                               \
    *(u16x8*)((Abuf) + aw1) = _w1;                                               \
} while (0)

// One K-tile. Ard: LDS buf holding A(t); Awr: buf for A(t+1); aW: raw-A bank
// to convert+write; IA: next A issue; bC: current B frags; bI/tB: next B issue.
#define FTILE(Ard, Awr, aW, IA, bC, bI, tB) do {                                 \
    ISSUE_B(bI, tB);                                                             \
    IA;                                                                          \
    bf16x8 afr[4][2];                                                            \
    _Pragma("unroll") for (int m = 0; m < 4; ++m)                                \
      _Pragma("unroll") for (int ks = 0; ks < 2; ++ks)                           \
        afr[m][ks] = *(const bf16x8*)((Ard) + a_off[ks] + m * 2048);             \
    WRITE_A(aW, Awr);                                                            \
    SETPRIO(1);                                                                  \
    _Pragma("unroll") for (int m = 0; m < 4; ++m)                                \
      _Pragma("unroll") for (int n = 0; n < 2; ++n) {                            \
        MFMA4(acc[m][n], afr[m][0], bC[n][0]);                                   \
        MFMA4(acc[m][n], afr[m][1], bC[n][1]);                                   \
      }                                                                          \
    SETPRIO(0);                                                                  \
    LGKM0(); PHASE_BAR(); CFENCE();                                              \
} while (0)

__global__ void __launch_bounds__(512, 4) gemm_fused_kernel(const float* __restrict__ X,
                                                            const unsigned short* __restrict__ B,
                                                            float* __restrict__ C) {
    __shared__ __align__(16) char lds[32768];
    char* As0 = lds;                 // 128 rows x 64 bf16 (128 B/row), 16 KB
    char* As1 = lds + 16384;

    int tid  = threadIdx.x;
    int lane = tid & 63;
    int wv   = tid >> 6;       // 0..7
    int wr   = wv >> 2;        // 0..1  (M: 2 x 64 rows)
    int wc   = wv & 3;         // 0..3  (N: 4 x 32 cols)
    (void)wv;

    // T1: XCD-chunked swizzle; 2048 blocks, cpx=256; tn fast -> 8 blocks sharing
    // one x-panel are consecutive -> same XCD -> panel L2-hot.
    int cpx = gridDim.x >> 3;
    int wid = ((int)blockIdx.x & 7) * cpx + ((int)blockIdx.x >> 3);
    int tn = wid & 7, tm = wid >> 3;
    int m0 = tm * 128, n0 = tn * 128;

    // A source: raw fp32 x; row = m0 + tid>>2, 16 consecutive floats at (tid&3)*16.
    const float* pA = X + ((size_t)(m0 + (tid >> 2)) << 10) + ((tid & 3) << 4);
    float4 aregE[4], aregO[4];       // distance-2 ping-pong banks

    // B source: per-lane direct frag address into unswizzled Wb.
    const char* pB = (const char*)B + (((size_t)(n0 + wc * 32 + (lane & 15))) << 11)
                     + ((lane >> 4) << 4);
    bf16x8 bBE[2][2], bBO[2][2];     // distance-1 ping-pong banks

    // A LDS write offsets (st-swizzle, proven): row*128 + 16*(blk ^ (row&7))
    int wrow = tid >> 2;
    int j0   = (tid & 3) << 1;
    int r7   = wrow & 7;
    int aw0  = wrow * 128 + (((j0    ) ^ r7) << 4);
    int aw1  = wrow * 128 + (((j0 + 1) ^ r7) << 4);

    // T2 swizzled A ds_read offsets (proven)
    int xa   = (lane & 7) << 4;
    int kq16 = (lane >> 4) << 4;
    int abase = (wr * 64 + (lane & 15)) * 128;
    int a_off[2] = { abase + (kq16 ^ xa), abase + ((64 + kq16) ^ xa) };

    f32x4 acc[4][2] = {};

    // ---- prologue ----
    ISSUE_B(bBE, 0);
    ISSUE_A(aregE, 0);
    ISSUE_A(aregO, 1);
    WRITE_A(aregE, As0);             // compiler waits for A(0) regs here
    LGKM0(); PHASE_BAR(); CFENCE();

    // ---- main loop: tiles 0..13 ----
    // even tile t: read As0 (A(t)); write aregO=A(t+1)->As1; issue aregE<-A(t+2);
    //              use bBE=B(t); issue bBO<-B(t+1).
    for (int t = 0; t < NKT - 2; t += 2) {
        FTILE(As0, As1, aregO, ISSUE_A(aregE, t + 2), bBE, bBO, t + 1);
        FTILE(As1, As0, aregE, ISSUE_A(aregO, t + 3), bBO, bBE, t + 2);
    }
    // ---- peeled tile 14: no further A issue ----
    FTILE(As0, As1, aregO, NOHOOK, bBE, bBO, NKT - 1);
    // ---- peeled tile 15: compute only ----
    {
        bf16x8 afr[4][2];
#pragma unroll
        for (int m = 0; m < 4; ++m)
#pragma unroll
            for (int ks = 0; ks < 2; ++ks)
                afr[m][ks] = *(const bf16x8*)(As1 + a_off[ks] + m * 2048);
        SETPRIO(1);
#pragma unroll
        for (int m = 0; m < 4; ++m)
#pragma unroll
            for (int n = 0; n < 2; ++n) {
                MFMA4(acc[m][n], afr[m][0], bBO[n][0]);
                MFMA4(acc[m][n], afr[m][1], bBO[n][1]);
            }
        SETPRIO(0);
    }

    // epilogue: C/D layout col = lane&15, row = (lane>>4)*4 + j (proven)
    float* Cp = C + ((size_t)(m0 + wr * 64)) * NCH + n0 + wc * 32;
    int cc = lane & 15;
    int rr = (lane >> 4) << 2;
#pragma unroll
    for (int m = 0; m < 4; ++m)
#pragma unroll
        for (int j = 0; j < 4; ++j) {
            float* rowp = Cp + ((size_t)(m * 16 + rr + j)) * NCH;
#pragma unroll
            for (int n = 0; n < 2; ++n)
                rowp[n * 16 + cc] = acc[m][n][j];
        }
}

// ---------------- fallback (ws too small): naive fp32 ----------------
__global__ void naive_kernel(const float* __restrict__ x, const float* __restrict__ w,
                             float* __restrict__ out) {
    int t = blockIdx.x;
    int o = blockIdx.y * 256 + threadIdx.x;
    const float* xr = x + (size_t)t * NCH;
    int r = o >> 6, oi = o & 63;
    float s = 0.f;
    for (int q = 0; q < 16; ++q) {
        const float* wq = w + (r * 16 + q) * 64;
        const float* xq = xr + q * 64;
#pragma unroll 8
        for (int j = 0; j < 64; ++j) s += xq[j] * wq[(oi - j) & 63];
    }
    out[(size_t)t * NCH + o] = s;
}

extern "C" void kernel_launch(void* const* d_in, const int* in_sizes, int n_in,
                              void* d_out, int out_size, void* d_ws, size_t ws_size,
                              hipStream_t stream) {
    const float* x = (const float*)d_in[0];
    const float* w = (const float*)d_in[1];
    float* out = (float*)d_out;

    const size_t needW = (size_t)NCH * NCH * sizeof(unsigned short);   // 2 MB

    if (ws_size >= needW) {
        unsigned short* Wb = (unsigned short*)d_ws;
        hipLaunchKernelGGL(build_w_kernel, dim3(NCH * 128 / 256), dim3(256), 0, stream, w, Wb);
        hipLaunchKernelGGL(gemm_fused_kernel, dim3(2048), dim3(512), 0, stream, x, Wb, out);
    } else {
        hipLaunchKernelGGL(naive_kernel, dim3(NTOK, 4), dim3(256), 0, stream, x, w, out);
    }
}

// Round 8
// 173.565 us; speedup vs baseline: 2.1079x; 2.1079x over previous
//
#include <hip/hip_runtime.h>
#include <stdint.h>

// BCM_Linear: out = x @ W^T, W[o,k] = w[o>>6, k>>6, (o-k)&63]  (1024x1024)
// M=32768, N=1024, K=1024. bf16 MFMA compute, fp32 in/out.
// Round 8: single-pass GEMM. A staged as RAW FP32 via global_load_lds
// (address-side swizzle on global src, linear LDS dest), converted fp32->bf16
// during LDS->fragment read via v_cvt_pk_bf16_f32. B fragments direct
// global->reg from L2-resident Wb (ping-pong pair). Drain VMCNT(0)+barrier
// per tile (R4-proven), 128x128 tile, 512 threads, 64KB LDS, 2 blocks/CU.

#define NTOK 32768
#define NCH  1024
#define BK   64
#define NKT  (NCH / BK)   // 16

typedef short bf16x8 __attribute__((ext_vector_type(8)));
typedef float f32x4  __attribute__((ext_vector_type(4)));
typedef unsigned short u16x8 __attribute__((ext_vector_type(8)));

static __device__ __forceinline__ unsigned short f2bf(float f) {
    unsigned int u = __float_as_uint(f);
    u += 0x7FFFu + ((u >> 16) & 1u);
    return (unsigned short)(u >> 16);
}

#define GLOAD16(gp, lp)                                                          \
    __builtin_amdgcn_global_load_lds(                                            \
        (const __attribute__((address_space(1))) unsigned int*)(gp),             \
        (__attribute__((address_space(3))) unsigned int*)(lp), 16, 0, 0)

// fp32x8 -> bf16x8 via v_cvt_pk_bf16_f32 (RNE; exists on gfx950, m214v22)
static __device__ __forceinline__ bf16x8 cvt8(f32x4 l, f32x4 h) {
    union { unsigned int w[4]; bf16x8 v; } u;
    asm("v_cvt_pk_bf16_f32 %0, %1, %2" : "=v"(u.w[0]) : "v"(l[0]), "v"(l[1]));
    asm("v_cvt_pk_bf16_f32 %0, %1, %2" : "=v"(u.w[1]) : "v"(l[2]), "v"(l[3]));
    asm("v_cvt_pk_bf16_f32 %0, %1, %2" : "=v"(u.w[2]) : "v"(h[0]), "v"(h[1]));
    asm("v_cvt_pk_bf16_f32 %0, %1, %2" : "=v"(u.w[3]) : "v"(h[2]), "v"(h[3]));
    return u.v;
}

// ---------------- kernel 1: circulant w -> dense bf16 W (N x K), unswizzled ----------------
__global__ void build_w_kernel(const float* __restrict__ w, unsigned short* __restrict__ Wb) {
    int i = blockIdx.x * blockDim.x + threadIdx.x;   // 0 .. 1024*128-1
    int o = i >> 7;
    int j = i & 127;
    int r = o >> 6;
    int q = j >> 3;
    const float* wrow = w + ((r * 16 + q) << 6);
    int k0 = j << 3;
    u16x8 v;
#pragma unroll
    for (int e = 0; e < 8; ++e) v[e] = f2bf(wrow[(o - (k0 + e)) & 63]);
    *(u16x8*)(Wb + (((size_t)o) << 10) + (j << 3)) = v;
}

// ---------------- kernel 2: single-pass 128x128 GEMM ----------------
#define PHASE_BAR() __builtin_amdgcn_s_barrier()
#define VMCNT0() asm volatile("s_waitcnt vmcnt(0)" ::: "memory")
#define SETPRIO(n) __builtin_amdgcn_s_setprio(n)
#define MFMA4(d, av, bv) d = __builtin_amdgcn_mfma_f32_16x16x32_bf16(av, bv, d, 0, 0, 0)
#define NOHOOK ((void)0)

// A staging: 128 rows x 64 fp32 cols = 32 KB per tile, 4 gload16/thread.
// LDS linear [row][256B]; global src address carries the inverse XOR swizzle.
#define STAGE_A(buf, t) do {                                                     \
    const char* _s = srcA + ((t) << 8);                                          \
    char* _d = (buf) + (wv << 10);                                               \
    GLOAD16(_s,                       _d);                                       \
    GLOAD16(_s + ((size_t)32 << 12),  _d + 8192);                                \
    GLOAD16(_s + ((size_t)64 << 12),  _d + 16384);                               \
    GLOAD16(_s + ((size_t)96 << 12),  _d + 24576);                               \
} while (0)

// B fragments direct global->reg from Wb (L2-resident), 4 x 16B per tile.
#define ISSUE_B(bank, t) do {                                                    \
    const char* _b = pB + ((t) << 7);                                            \
    bank[0][0] = *(const bf16x8*)(_b);                                           \
    bank[0][1] = *(const bf16x8*)(_b + 64);                                      \
    bank[1][0] = *(const bf16x8*)(_b + 32768);                                   \
    bank[1][1] = *(const bf16x8*)(_b + 32768 + 64);                              \
} while (0)

// One K-tile: stage A(t+1), issue B(t+1), read fp32 A-frags + cvt, MFMA, drain.
#define KSTEP(Ard, STG, bC, IB) do {                                             \
    STG; IB;                                                                     \
    _Pragma("unroll") for (int m = 0; m < 4; ++m) {                              \
        f32x4 lo0 = *(const f32x4*)((Ard) + a_off2[0][0] + m * 4096);            \
        f32x4 hi0 = *(const f32x4*)((Ard) + a_off2[0][1] + m * 4096);            \
        f32x4 lo1 = *(const f32x4*)((Ard) + a_off2[1][0] + m * 4096);            \
        f32x4 hi1 = *(const f32x4*)((Ard) + a_off2[1][1] + m * 4096);            \
        bf16x8 a0 = cvt8(lo0, hi0);                                              \
        bf16x8 a1 = cvt8(lo1, hi1);                                              \
        SETPRIO(1);                                                              \
        _Pragma("unroll") for (int n = 0; n < 2; ++n) {                          \
            MFMA4(acc[m][n], a0, bC[n][0]);                                      \
            MFMA4(acc[m][n], a1, bC[n][1]);                                      \
        }                                                                        \
        SETPRIO(0);                                                              \
    }                                                                            \
    VMCNT0(); PHASE_BAR();                                                       \
} while (0)

__global__ void __launch_bounds__(512, 4) gemm_direct_kernel(const float* __restrict__ X,
                                                             const unsigned short* __restrict__ B,
                                                             float* __restrict__ C) {
    __shared__ __align__(16) char lds[65536];
    char* As0 = lds;                 // 128 rows x 256 B fp32 (32 KB)
    char* As1 = lds + 32768;

    int tid  = threadIdx.x;
    int lane = tid & 63;
    int wv   = tid >> 6;       // 0..7
    int wr   = wv >> 2;        // 0..1  (M: 2 x 64 rows)
    int wc   = wv & 3;         // 0..3  (N: 4 x 32 cols)

    // T1: XCD-chunked swizzle; 2048 blocks, cpx=256; tn fast -> 8 blocks sharing
    // one x-panel are consecutive -> same XCD -> x panel L2-hot.
    int cpx = gridDim.x >> 3;
    int wid = ((int)blockIdx.x & 7) * cpx + ((int)blockIdx.x >> 3);
    int tn = wid & 7, tm = wid >> 3;
    int m0 = tm * 128, n0 = tn * 128;

    // A staging source: lane covers (row = wv*4 + lane>>4 [+32p], 16B-block lane&15),
    // global block index pre-XOR'd so linear LDS + XOR'd read compose to identity.
    {
    }
    int arow = wv * 4 + (lane >> 4);          // base row (pass p adds 32)
    int ablk = (lane & 15) ^ (arow & 7);      // swizzled source 16B-block
    const char* srcA = (const char*)X + (((size_t)(m0 + arow)) << 12) + ((size_t)ablk << 4);

    // B source: per-lane frag address into unswizzled Wb.
    const char* pB = (const char*)B + (((size_t)(n0 + wc * 32 + (lane & 15))) << 11)
                     + ((lane >> 4) << 4);
    bf16x8 bE[2][2], bO[2][2];

    // A fragment read offsets (fp32, swizzled): row = wr*64 + (lane&15) (+m*16),
    // 16B-block = (ks*8 + (lane>>4)*2 + h) ^ (lane&7);  row stride 256 B.
    int rbase = (wr * 64 + (lane & 15)) * 256;
    int r7    = lane & 7;
    int g2    = (lane >> 4) << 1;
    int a_off2[2][2];
#pragma unroll
    for (int ks = 0; ks < 2; ++ks)
#pragma unroll
        for (int h = 0; h < 2; ++h)
            a_off2[ks][h] = rbase + ((((ks << 3) + g2 + h) ^ r7) << 4);

    f32x4 acc[4][2] = {};

    // ---- prologue: tile 0 ----
    STAGE_A(As0, 0);
    ISSUE_B(bE, 0);
    VMCNT0(); PHASE_BAR();

    // ---- main loop: tiles 0..13 ----
    for (int t = 0; t < NKT - 2; t += 2) {
        KSTEP(As0, STAGE_A(As1, t + 1), bE, ISSUE_B(bO, t + 1));
        KSTEP(As1, STAGE_A(As0, t + 2), bO, ISSUE_B(bE, t + 2));
    }
    // ---- tile 14: stage tile 15, load its B ----
    KSTEP(As0, STAGE_A(As1, NKT - 1), bE, ISSUE_B(bO, NKT - 1));
    // ---- tile 15: compute only ----
    KSTEP(As1, NOHOOK, bO, NOHOOK);

    // epilogue: C/D layout col = lane&15, row = (lane>>4)*4 + j (proven)
    float* Cp = C + ((size_t)(m0 + wr * 64)) * NCH + n0 + wc * 32;
    int cc = lane & 15;
    int rr = (lane >> 4) << 2;
#pragma unroll
    for (int m = 0; m < 4; ++m)
#pragma unroll
        for (int j = 0; j < 4; ++j) {
            float* rowp = Cp + ((size_t)(m * 16 + rr + j)) * NCH;
#pragma unroll
            for (int n = 0; n < 2; ++n)
                rowp[n * 16 + cc] = acc[m][n][j];
        }
}

// ---------------- fallback (ws too small): naive fp32 ----------------
__global__ void naive_kernel(const float* __restrict__ x, const float* __restrict__ w,
                             float* __restrict__ out) {
    int t = blockIdx.x;
    int o = blockIdx.y * 256 + threadIdx.x;
    const float* xr = x + (size_t)t * NCH;
    int r = o >> 6, oi = o & 63;
    float s = 0.f;
    for (int q = 0; q < 16; ++q) {
        const float* wq = w + (r * 16 + q) * 64;
        const float* xq = xr + q * 64;
#pragma unroll 8
        for (int j = 0; j < 64; ++j) s += xq[j] * wq[(oi - j) & 63];
    }
    out[(size_t)t * NCH + o] = s;
}

extern "C" void kernel_launch(void* const* d_in, const int* in_sizes, int n_in,
                              void* d_out, int out_size, void* d_ws, size_t ws_size,
                              hipStream_t stream) {
    const float* x = (const float*)d_in[0];
    const float* w = (const float*)d_in[1];
    float* out = (float*)d_out;

    const size_t needW = (size_t)NCH * NCH * sizeof(unsigned short);   // 2 MB

    if (ws_size >= needW) {
        unsigned short* Wb = (unsigned short*)d_ws;
        hipLaunchKernelGGL(build_w_kernel, dim3(NCH * 128 / 256), dim3(256), 0, stream, w, Wb);
        hipLaunchKernelGGL(gemm_direct_kernel, dim3(2048), dim3(512), 0, stream, x, Wb, out);
    } else {
        hipLaunchKernelGGL(naive_kernel, dim3(NTOK, 4), dim3(256), 0, stream, x, w, out);
    }
}

// Round 9
// 110.645 us; speedup vs baseline: 3.3066x; 1.5687x over previous
//
#include <hip/hip_runtime.h>
#include <stdint.h>

// BCM_Linear: out = x @ W^T, W[o,k] = w[o>>6, k>>6, (o-k)&63]  (1024x1024)
// M=32768, N=1024, K=1024. bf16 MFMA compute, fp32 in/out.
// Round 9: single-pass fused GEMM, every component in proven geometry.
//  - A staged RAW FP32 via global_load_lds into TWO 128B-stride planes per
//    buffer (k-halves), inverse-swizzled global src, XOR'd ds_read_b128 pairs
//    + v_cvt_pk_bf16_f32 on read. (128B stride + (row&7) XOR = R2/R4 proven
//    0-conflict geometry; R8's 256B-stride layout was the conflict bug.)
//  - B bf16 via pre-swizzled Wb + global_load_lds (R2/R4 verbatim).
//  - 128x256 tile, 8 waves x (64x64), BK=64, LDS 128KB, VMCNT(0)+bar per tile.

#define NTOK 32768
#define NCH  1024
#define BK   64
#define NKT  (NCH / BK)   // 16

typedef short bf16x8 __attribute__((ext_vector_type(8)));
typedef float f32x4  __attribute__((ext_vector_type(4)));
typedef unsigned short u16x8 __attribute__((ext_vector_type(8)));

static __device__ __forceinline__ unsigned short f2bf(float f) {
    unsigned int u = __float_as_uint(f);
    u += 0x7FFFu + ((u >> 16) & 1u);
    return (unsigned short)(u >> 16);
}

#define GLOAD16(gp, lp)                                                          \
    __builtin_amdgcn_global_load_lds(                                            \
        (const __attribute__((address_space(1))) unsigned int*)(gp),             \
        (__attribute__((address_space(3))) unsigned int*)(lp), 16, 0, 0)

// fp32x8 -> bf16x8 (RNE) via v_cvt_pk_bf16_f32
static __device__ __forceinline__ bf16x8 cvt8(f32x4 l, f32x4 h) {
    union { unsigned int w[4]; bf16x8 v; } u;
    asm("v_cvt_pk_bf16_f32 %0, %1, %2" : "=v"(u.w[0]) : "v"(l[0]), "v"(l[1]));
    asm("v_cvt_pk_bf16_f32 %0, %1, %2" : "=v"(u.w[1]) : "v"(l[2]), "v"(l[3]));
    asm("v_cvt_pk_bf16_f32 %0, %1, %2" : "=v"(u.w[2]) : "v"(h[0]), "v"(h[1]));
    asm("v_cvt_pk_bf16_f32 %0, %1, %2" : "=v"(u.w[3]) : "v"(h[2]), "v"(h[3]));
    return u.v;
}

// ---------------- kernel 1: circulant w -> dense bf16 W, PRE-SWIZZLED (R2 proven) ----------------
__global__ void build_w_kernel(const float* __restrict__ w, unsigned short* __restrict__ Wb) {
    int i = blockIdx.x * blockDim.x + threadIdx.x;   // 0 .. 1024*128-1
    int o = i >> 7;
    int j = i & 127;                // 16B-block index within 2048B row
    int r = o >> 6;
    int q = j >> 3;
    const float* wrow = w + ((r * 16 + q) << 6);
    int k0 = j << 3;
    u16x8 v;
#pragma unroll
    for (int e = 0; e < 8; ++e) v[e] = f2bf(wrow[(o - (k0 + e)) & 63]);
    int js = (j & ~7) | ((j & 7) ^ (o & 7));   // st-swizzle within each 128B chunk
    *(u16x8*)(Wb + (((size_t)o) << 10) + (js << 3)) = v;
}

// ---------------- kernel 2: fused 128x256 GEMM ----------------
#define PHASE_BAR() __builtin_amdgcn_s_barrier()
#define VMCNT0() asm volatile("s_waitcnt vmcnt(0)" ::: "memory")
#define CFENCE() asm volatile("" ::: "memory")
#define SETPRIO(n) __builtin_amdgcn_s_setprio(n)
#define MFMA4(d, av, bv) d = __builtin_amdgcn_mfma_f32_16x16x32_bf16(av, bv, d, 0, 0, 0)
#define NOHOOK ((void)0)

// A staging: 128 rows x 64 fp32 = 32 KB per tile, as 2 planes x 2 halves,
// 4 gload16/thread. Source carries inverse XOR swizzle; LDS dest linear.
#define STAGE_A(buf, tk) do {                                                    \
    const char* _s = srcA + ((tk) << 8);                                         \
    char* _d = (buf) + (wv << 10);                                               \
    GLOAD16(_s,                        _d);                                      \
    GLOAD16(_s + ((size_t)64 << 12),   _d + 8192);                               \
    GLOAD16(_s + 128,                  _d + 16384);                              \
    GLOAD16(_s + 128 + ((size_t)64 << 12), _d + 24576);                          \
} while (0)

// B staging: 256 rows x 64 bf16 = 32 KB per tile, 4 gload16/thread (pre-swizzled Wb).
#define STAGE_B(buf, tk) do {                                                    \
    const char* _s = srcB + ((tk) << 7);                                         \
    char* _d = (buf) + (wv << 10);                                               \
    GLOAD16(_s,                        _d);                                      \
    GLOAD16(_s + ((size_t)64 << 11),   _d + 8192);                               \
    GLOAD16(_s + ((size_t)128 << 11),  _d + 16384);                              \
    GLOAD16(_s + ((size_t)192 << 11),  _d + 24576);                              \
} while (0)

// One K-tile: stage hook first (max issue->drain distance), B frags, then per-m
// {A fp32 reads -> cvt -> 8 MFMA}. Single drain + barrier at the end.
#define KSTEP(Ard, Brd, STG) do {                                                \
    STG;                                                                         \
    bf16x8 bfr[4][2];                                                            \
    _Pragma("unroll") for (int n = 0; n < 4; ++n)                                \
      _Pragma("unroll") for (int ks = 0; ks < 2; ++ks)                           \
        bfr[n][ks] = *(const bf16x8*)((Brd) + b_off[ks] + n * 2048);             \
    SETPRIO(1);                                                                  \
    _Pragma("unroll") for (int m = 0; m < 4; ++m) {                              \
        f32x4 lo0 = *(const f32x4*)((Ard) + a_rd[0][0] + m * 2048);              \
        f32x4 hi0 = *(const f32x4*)((Ard) + a_rd[0][1] + m * 2048);              \
        f32x4 lo1 = *(const f32x4*)((Ard) + a_rd[1][0] + m * 2048);              \
        f32x4 hi1 = *(const f32x4*)((Ard) + a_rd[1][1] + m * 2048);              \
        bf16x8 a0 = cvt8(lo0, hi0);                                              \
        bf16x8 a1 = cvt8(lo1, hi1);                                              \
        _Pragma("unroll") for (int n = 0; n < 4; ++n) {                          \
            MFMA4(acc[m][n], a0, bfr[n][0]);                                     \
            MFMA4(acc[m][n], a1, bfr[n][1]);                                     \
        }                                                                        \
    }                                                                            \
    SETPRIO(0);                                                                  \
    VMCNT0(); PHASE_BAR(); CFENCE();                                             \
} while (0)

__global__ void __launch_bounds__(512, 1) gemm_fused_kernel(const float* __restrict__ X,
                                                            const unsigned short* __restrict__ B,
                                                            float* __restrict__ C) {
    __shared__ __align__(16) char lds[131072];
    char* As0 = lds;                 // 2 planes x [128 rows][128 B] = 32 KB
    char* As1 = lds + 32768;
    char* Bs0 = lds + 65536;         // [256 rows][128 B] = 32 KB
    char* Bs1 = lds + 98304;

    int tid  = threadIdx.x;
    int lane = tid & 63;
    int wv   = tid >> 6;       // 0..7
    int wr   = wv >> 2;        // 0..1  (M: 2 x 64 rows)
    int wc   = wv & 3;         // 0..3  (N: 4 x 64 cols)

    // T1: XCD-chunked swizzle; 1024 blocks (%8==0 bijective), tn fast.
    int cpx = gridDim.x >> 3;
    int wid = ((int)blockIdx.x & 7) * cpx + ((int)blockIdx.x >> 3);
    int tn = wid & 3, tm = wid >> 2;
    int m0 = tm * 128, n0 = tn * 256;

    // A staging source: row = m0 + (tid>>3) (+64 for upper half), 16B-block
    // (tid&7) ^ (row&7) -> inverse swizzle; planes at +0 / +128 B within row.
    const char* srcA = (const char*)X + (((size_t)(m0 + (tid >> 3))) << 12)
                     + ((((tid & 7) ^ ((tid >> 3) & 7))) << 4);

    // B staging source (pre-swizzled Wb -> linear gather)
    const char* srcB = (const char*)B + (((size_t)(n0 + (tid >> 3))) << 11) + ((tid & 7) << 4);

    // A frag reads (fp32, proven 128B-stride geometry):
    // plane ks at ks*16384; row r = wr*64 + m*16 + (lane&15), stride 128 B;
    // 16B-granule = ((lane>>4)*2 + h) ^ (lane&7).
    int r7   = lane & 7;
    int g2   = (lane >> 4) << 1;
    int abase = (wr * 64 + (lane & 15)) * 128;
    int a_rd[2][2];
#pragma unroll
    for (int ks = 0; ks < 2; ++ks)
#pragma unroll
        for (int h = 0; h < 2; ++h)
            a_rd[ks][h] = ks * 16384 + abase + (((g2 + h) ^ r7) << 4);

    // B frag reads (bf16, R2/R4 verbatim)
    int kq16 = (lane >> 4) << 4;
    int bbase = (wc * 64 + (lane & 15)) * 128;
    int b_off[2] = { bbase + ((kq16 + 0)  ^ (r7 << 4)),
                     bbase + ((kq16 + 64) ^ (r7 << 4)) };

    f32x4 acc[4][4] = {};

    // ---- prologue ----
    STAGE_A(As0, 0); STAGE_B(Bs0, 0);
    VMCNT0(); PHASE_BAR(); CFENCE();

    // ---- main loop ----
    for (int t = 0; t < NKT; t += 2) {
        KSTEP(As0, Bs0, { STAGE_A(As1, t + 1); STAGE_B(Bs1, t + 1); });
        if (t + 2 < NKT) {
            KSTEP(As1, Bs1, { STAGE_A(As0, t + 2); STAGE_B(Bs0, t + 2); });
        } else {
            KSTEP(As1, Bs1, NOHOOK);
        }
    }

    // epilogue: C/D layout col = lane&15, row = (lane>>4)*4 + j (proven)
    float* Cp = C + ((size_t)(m0 + wr * 64)) * NCH + n0 + wc * 64;
    int cc = lane & 15;
    int rr = (lane >> 4) << 2;
#pragma unroll
    for (int m = 0; m < 4; ++m)
#pragma unroll
        for (int j = 0; j < 4; ++j) {
            float* rowp = Cp + ((size_t)(m * 16 + rr + j)) * NCH;
#pragma unroll
            for (int n = 0; n < 4; ++n)
                rowp[n * 16 + cc] = acc[m][n][j];
        }
}

// ---------------- fallback (ws too small): naive fp32 ----------------
__global__ void naive_kernel(const float* __restrict__ x, const float* __restrict__ w,
                             float* __restrict__ out) {
    int t = blockIdx.x;
    int o = blockIdx.y * 256 + threadIdx.x;
    const float* xr = x + (size_t)t * NCH;
    int r = o >> 6, oi = o & 63;
    float s = 0.f;
    for (int q = 0; q < 16; ++q) {
        const float* wq = w + (r * 16 + q) * 64;
        const float* xq = xr + q * 64;
#pragma unroll 8
        for (int j = 0; j < 64; ++j) s += xq[j] * wq[(oi - j) & 63];
    }
    out[(size_t)t * NCH + o] = s;
}

extern "C" void kernel_launch(void* const* d_in, const int* in_sizes, int n_in,
                              void* d_out, int out_size, void* d_ws, size_t ws_size,
                              hipStream_t stream) {
    const float* x = (const float*)d_in[0];
    const float* w = (const float*)d_in[1];
    float* out = (float*)d_out;

    const size_t needW = (size_t)NCH * NCH * sizeof(unsigned short);   // 2 MB

    if (ws_size >= needW) {
        unsigned short* Wb = (unsigned short*)d_ws;
        hipLaunchKernelGGL(build_w_kernel, dim3(NCH * 128 / 256), dim3(256), 0, stream, w, Wb);
        hipLaunchKernelGGL(gemm_fused_kernel, dim3(1024), dim3(512), 0, stream, x, Wb, out);
    } else {
        hipLaunchKernelGGL(naive_kernel, dim3(NTOK, 4), dim3(256), 0, stream, x, w, out);
    }
}

// Round 10
// 110.532 us; speedup vs baseline: 3.3099x; 1.0010x over previous
//
#include <hip/hip_runtime.h>
#include <stdint.h>

// BCM_Linear: out = x @ W^T, W[o,k] = w[o>>6, k>>6, (o-k)&63]  (1024x1024)
// M=32768, N=1024, K=1024. bf16 MFMA compute, fp32 in/out.
// Round 10: single-pass fused GEMM.
//  - A staged RAW FP32 via global_load_lds, 256B rows with 4-bit granule
//    remap Gl = q|h<<2|ks<<3 -> reads are ((q|h<<2)^p) low-3 XOR = the
//    empirically-proven 0-conflict pattern (R9's (2q|h)^p was the conflict).
//  - A single-buffered in two row-half buffers, phased P1/P2; B dbuf via
//    pre-swizzled Wb (R2/R4 verbatim). ALL vmem = global_load_lds ->
//    counted VMCNT(4)/(2) FIFO-safe. 128x128 tile, 8 waves (4x2, 32x64 each),
//    64KB LDS -> 2 blocks/CU.

#define NTOK 32768
#define NCH  1024
#define NKT  16

typedef short bf16x8 __attribute__((ext_vector_type(8)));
typedef float f32x4  __attribute__((ext_vector_type(4)));
typedef unsigned short u16x8 __attribute__((ext_vector_type(8)));

static __device__ __forceinline__ unsigned short f2bf(float f) {
    unsigned int u = __float_as_uint(f);
    u += 0x7FFFu + ((u >> 16) & 1u);
    return (unsigned short)(u >> 16);
}

#define GLOAD16(gp, lp)                                                          \
    __builtin_amdgcn_global_load_lds(                                            \
        (const __attribute__((address_space(1))) unsigned int*)(gp),             \
        (__attribute__((address_space(3))) unsigned int*)(lp), 16, 0, 0)

// fp32x8 -> bf16x8 (RNE) via v_cvt_pk_bf16_f32
static __device__ __forceinline__ bf16x8 cvt8(f32x4 l, f32x4 h) {
    union { unsigned int w[4]; bf16x8 v; } u;
    asm("v_cvt_pk_bf16_f32 %0, %1, %2" : "=v"(u.w[0]) : "v"(l[0]), "v"(l[1]));
    asm("v_cvt_pk_bf16_f32 %0, %1, %2" : "=v"(u.w[1]) : "v"(l[2]), "v"(l[3]));
    asm("v_cvt_pk_bf16_f32 %0, %1, %2" : "=v"(u.w[2]) : "v"(h[0]), "v"(h[1]));
    asm("v_cvt_pk_bf16_f32 %0, %1, %2" : "=v"(u.w[3]) : "v"(h[2]), "v"(h[3]));
    return u.v;
}

// ---------------- kernel 1: circulant w -> dense bf16 W, PRE-SWIZZLED (R2 proven) ----------------
__global__ void build_w_kernel(const float* __restrict__ w, unsigned short* __restrict__ Wb) {
    int i = blockIdx.x * blockDim.x + threadIdx.x;   // 0 .. 1024*128-1
    int o = i >> 7;
    int j = i & 127;
    int r = o >> 6;
    int q = j >> 3;
    const float* wrow = w + ((r * 16 + q) << 6);
    int k0 = j << 3;
    u16x8 v;
#pragma unroll
    for (int e = 0; e < 8; ++e) v[e] = f2bf(wrow[(o - (k0 + e)) & 63]);
    int js = (j & ~7) | ((j & 7) ^ (o & 7));
    *(u16x8*)(Wb + (((size_t)o) << 10) + (js << 3)) = v;
}

// ---------------- kernel 2: fused 128x128 GEMM ----------------
#define BAR() __builtin_amdgcn_s_barrier()
#define LGKM0() asm volatile("s_waitcnt lgkmcnt(0)" ::: "memory")
#define VMCNT(n) asm volatile("s_waitcnt vmcnt(" #n ")" ::: "memory")
#define CFENCE() asm volatile("" ::: "memory")
#define SETPRIO(n) __builtin_amdgcn_s_setprio(n)
#define MFMA4(d, av, bv) d = __builtin_amdgcn_mfma_f32_16x16x32_bf16(av, bv, d, 0, 0, 0)

// A half-tile stage: 64 LDS rows x 256 B = 16 KB, 2 gload16/thread.
#define STAGE_AH(buf, rowoff, t) do {                                            \
    const char* _s = srcA + (((size_t)(rowoff)) << 12) + ((t) << 8);             \
    char* _d = (buf) + (wv << 10);                                               \
    GLOAD16(_s, _d);                                                             \
    GLOAD16(_s + ((size_t)64 << 12), _d + 8192);                                 \
} while (0)

// B stage: 128 rows x 128 B = 16 KB, 2 gload16/thread (pre-swizzled Wb).
#define STAGE_B(buf, t) do {                                                     \
    const char* _s = srcB + ((t) << 7);                                          \
    char* _d = (buf) + (wv << 10);                                               \
    GLOAD16(_s, _d);                                                             \
    GLOAD16(_s + ((size_t)64 << 11), _d + 8192);                                 \
} while (0)

// A fragment read+cvt from half-buffer (4x ds_read_b128 fp32 -> 2 bf16x8)
#define AREAD(aF, buf) do {                                                      \
    f32x4 _l0 = *(const f32x4*)((buf) + a_rd[0][0]);                             \
    f32x4 _h0 = *(const f32x4*)((buf) + a_rd[0][1]);                             \
    f32x4 _l1 = *(const f32x4*)((buf) + a_rd[1][0]);                             \
    f32x4 _h1 = *(const f32x4*)((buf) + a_rd[1][1]);                             \
    aF[0] = cvt8(_l0, _h0);                                                      \
    aF[1] = cvt8(_l1, _h1);                                                      \
} while (0)

// One K-tile (2 phases). LAST skips prefetch and drains fully.
#define BODY(t, Bcur, Bnxt, LAST) do {                                           \
    bf16x8 aF0[2], aF1[2], bfr[4][2];                                            \
    AREAD(aF0, Ah0);                                                             \
    _Pragma("unroll") for (int n = 0; n < 4; ++n)                                \
      _Pragma("unroll") for (int ks = 0; ks < 2; ++ks)                           \
        bfr[n][ks] = *(const bf16x8*)((Bcur) + b_off[ks] + n * 2048);            \
    LGKM0(); BAR();                      /* all P1 reads done */                 \
    if (!(LAST)) { STAGE_AH(Ah0, 0, (t) + 1); STAGE_B(Bnxt, (t) + 1); }          \
    SETPRIO(1);                                                                  \
    _Pragma("unroll") for (int n = 0; n < 4; ++n) {                              \
        MFMA4(acc[0][n], aF0[0], bfr[n][0]);                                     \
        MFMA4(acc[0][n], aF0[1], bfr[n][1]);                                     \
    }                                                                            \
    SETPRIO(0);                                                                  \
    if (LAST) { VMCNT(0); } else { VMCNT(4); }   /* H1(t) landed */              \
    BAR();                                                                       \
    AREAD(aF1, Ah1);                                                             \
    LGKM0();                                                                     \
    SETPRIO(1);                                                                  \
    _Pragma("unroll") for (int n = 0; n < 4; ++n) {                              \
        MFMA4(acc[1][n], aF1[0], bfr[n][0]);                                     \
        MFMA4(acc[1][n], aF1[1], bfr[n][1]);                                     \
    }                                                                            \
    SETPRIO(0);                                                                  \
    if (!(LAST)) {                                                               \
        BAR();                           /* all P2 reads done */                 \
        STAGE_AH(Ah1, 16, (t) + 1);                                              \
        VMCNT(2);                        /* H0(t+1)+B(t+1) landed */             \
        BAR(); CFENCE();                                                         \
    }                                                                            \
} while (0)

__global__ void __launch_bounds__(512, 4) gemm_fused_kernel(const float* __restrict__ X,
                                                            const unsigned short* __restrict__ B,
                                                            float* __restrict__ C) {
    __shared__ __align__(16) char lds[65536];
    char* Ah0 = lds;                 // 64 rows x 256 B (glob rows ==0..15 mod 32)
    char* Ah1 = lds + 16384;         // glob rows ==16..31 mod 32
    char* Bs0 = lds + 32768;
    char* Bs1 = lds + 49152;

    int tid  = threadIdx.x;
    int lane = tid & 63;
    int wv   = tid >> 6;       // 0..7
    int wr   = wv >> 1;        // 0..3  (M: 4 x 32 rows)
    int wc   = wv & 1;         // 0..1  (N: 2 x 64 cols)

    // T1: XCD-chunked swizzle (2048 blocks, R4 verbatim)
    int cpx = gridDim.x >> 3;
    int wid = ((int)blockIdx.x & 7) * cpx + ((int)blockIdx.x >> 3);
    int tn = wid & 7, tm = wid >> 3;
    int m0 = tm * 128, n0 = tn * 128;

    // ---- A staging source (granule-remapped, inverse-swizzled) ----
    // thread covers LDS row lr0 = tid>>4 (pass0; +32 pass1), phys granule G = tid&15.
    // glob row = (lr0&15) + 32*(lr0>>4)  [+64 pass1; +16 for Ah1]
    // logical granule Gl = (G&8) | ((G ^ (row&7)) & 7); byte-in-K-tile:
    // (Gl>>3)*128 + (Gl&3)*32 + ((Gl>>2)&1)*16.
    int lr0  = tid >> 4;
    int grow = (lr0 & 15) | ((lr0 & 16) << 1);
    int G    = tid & 15;
    int Gl   = (G & 8) | ((G ^ (lr0 & 7)) & 7);
    int byB  = ((Gl >> 3) << 7) | ((Gl & 3) << 5) | (((Gl >> 2) & 1) << 4);
    const char* srcA = (const char*)X + (((size_t)(m0 + grow)) << 12) + byB;

    // B staging source (pre-swizzled Wb -> linear gather, R4 verbatim)
    const char* srcB = (const char*)B + (((size_t)(n0 + (tid >> 3))) << 11) + ((tid & 7) << 4);

    // ---- A fragment read offsets: lr = wr*16 + (lane&15), stride 256 B;
    // granule = (q | h<<2 | ks<<3) ^ p  (XOR low-3 only; proven bank pattern)
    int p = lane & 7;
    int q = lane >> 4;
    int abase = (wr * 16 + (lane & 15)) * 256;
    int a_rd[2][2];
#pragma unroll
    for (int ks = 0; ks < 2; ++ks)
#pragma unroll
        for (int h = 0; h < 2; ++h)
            a_rd[ks][h] = abase + (((q | (h << 2) | (ks << 3)) ^ p) << 4);

    // B fragment read offsets (R2/R4 proven verbatim)
    int kq16 = q << 4;
    int bbase = (wc * 64 + (lane & 15)) * 128;
    int b_off[2] = { bbase + ((kq16 + 0)  ^ (p << 4)),
                     bbase + ((kq16 + 64) ^ (p << 4)) };

    f32x4 acc[2][4] = {};

    // ---- prologue: full tile 0 ----
    STAGE_AH(Ah0, 0, 0); STAGE_AH(Ah1, 16, 0); STAGE_B(Bs0, 0);
    VMCNT(0); BAR(); CFENCE();

    // ---- main loop ----
    for (int t = 0; t < NKT - 2; t += 2) {
        BODY(t,     Bs0, Bs1, false);
        BODY(t + 1, Bs1, Bs0, false);
    }
    BODY(NKT - 2, Bs0, Bs1, false);
    BODY(NKT - 1, Bs1, Bs0, true);

    // ---- epilogue: C/D layout col = lane&15, row = (lane>>4)*4 + j (proven) ----
    float* Cp = C + ((size_t)(m0 + wr * 32)) * NCH + n0 + wc * 64;
    int cc = lane & 15;
    int rr = (lane >> 4) << 2;
#pragma unroll
    for (int m = 0; m < 2; ++m)
#pragma unroll
        for (int j = 0; j < 4; ++j) {
            float* rowp = Cp + ((size_t)(m * 16 + rr + j)) * NCH;
#pragma unroll
            for (int n = 0; n < 4; ++n)
                rowp[n * 16 + cc] = acc[m][n][j];
        }
}

// ---------------- fallback (ws too small): naive fp32 ----------------
__global__ void naive_kernel(const float* __restrict__ x, const float* __restrict__ w,
                             float* __restrict__ out) {
    int t = blockIdx.x;
    int o = blockIdx.y * 256 + threadIdx.x;
    const float* xr = x + (size_t)t * NCH;
    int r = o >> 6, oi = o & 63;
    float s = 0.f;
    for (int qq = 0; qq < 16; ++qq) {
        const float* wq = w + (r * 16 + qq) * 64;
        const float* xq = xr + qq * 64;
#pragma unroll 8
        for (int j = 0; j < 64; ++j) s += xq[j] * wq[(oi - j) & 63];
    }
    out[(size_t)t * NCH + o] = s;
}

extern "C" void kernel_launch(void* const* d_in, const int* in_sizes, int n_in,
                              void* d_out, int out_size, void* d_ws, size_t ws_size,
                              hipStream_t stream) {
    const float* x = (const float*)d_in[0];
    const float* w = (const float*)d_in[1];
    float* out = (float*)d_out;

    const size_t needW = (size_t)NCH * NCH * sizeof(unsigned short);   // 2 MB

    if (ws_size >= needW) {
        unsigned short* Wb = (unsigned short*)d_ws;
        hipLaunchKernelGGL(build_w_kernel, dim3(NCH * 128 / 256), dim3(256), 0, stream, w, Wb);
        hipLaunchKernelGGL(gemm_fused_kernel, dim3(2048), dim3(512), 0, stream, x, Wb, out);
    } else {
        hipLaunchKernelGGL(naive_kernel, dim3(NTOK, 4), dim3(256), 0, stream, x, w, out);
    }
}

// Round 11
// 105.823 us; speedup vs baseline: 3.4572x; 1.0445x over previous
//
#include <hip/hip_runtime.h>
#include <stdint.h>

// BCM_Linear: out = x @ W^T, W[o,k] = w[o>>6, k>>6, (o-k)&63]  (1024x1024)
// M=32768, N=1024, K=1024. bf16 MFMA compute, fp32 in/out.
// Round 11: fused single-pass GEMM == R10 except A LDS layout.
//  A tile per half-buffer: 2 planes (ks) x [64 rows][128 B] fp32.
//  Row stride 128 B -> addr bit7 = row&1 varies per lane (the empirically
//  0-conflict property R8/R9/R10 all violated); plane offset 8192 neutral.
//  Phys granule = (q|h<<2)^p; logical rotation folded into global src addr.

#define NTOK 32768
#define NCH  1024
#define NKT  16

typedef short bf16x8 __attribute__((ext_vector_type(8)));
typedef float f32x4  __attribute__((ext_vector_type(4)));
typedef unsigned short u16x8 __attribute__((ext_vector_type(8)));

static __device__ __forceinline__ unsigned short f2bf(float f) {
    unsigned int u = __float_as_uint(f);
    u += 0x7FFFu + ((u >> 16) & 1u);
    return (unsigned short)(u >> 16);
}

#define GLOAD16(gp, lp)                                                          \
    __builtin_amdgcn_global_load_lds(                                            \
        (const __attribute__((address_space(1))) unsigned int*)(gp),             \
        (__attribute__((address_space(3))) unsigned int*)(lp), 16, 0, 0)

// fp32x8 -> bf16x8 (RNE) via v_cvt_pk_bf16_f32
static __device__ __forceinline__ bf16x8 cvt8(f32x4 l, f32x4 h) {
    union { unsigned int w[4]; bf16x8 v; } u;
    asm("v_cvt_pk_bf16_f32 %0, %1, %2" : "=v"(u.w[0]) : "v"(l[0]), "v"(l[1]));
    asm("v_cvt_pk_bf16_f32 %0, %1, %2" : "=v"(u.w[1]) : "v"(l[2]), "v"(l[3]));
    asm("v_cvt_pk_bf16_f32 %0, %1, %2" : "=v"(u.w[2]) : "v"(h[0]), "v"(h[1]));
    asm("v_cvt_pk_bf16_f32 %0, %1, %2" : "=v"(u.w[3]) : "v"(h[2]), "v"(h[3]));
    return u.v;
}

// ---------------- kernel 1: circulant w -> dense bf16 W, PRE-SWIZZLED (R2 proven) ----------------
__global__ void build_w_kernel(const float* __restrict__ w, unsigned short* __restrict__ Wb) {
    int i = blockIdx.x * blockDim.x + threadIdx.x;   // 0 .. 1024*128-1
    int o = i >> 7;
    int j = i & 127;
    int r = o >> 6;
    int q = j >> 3;
    const float* wrow = w + ((r * 16 + q) << 6);
    int k0 = j << 3;
    u16x8 v;
#pragma unroll
    for (int e = 0; e < 8; ++e) v[e] = f2bf(wrow[(o - (k0 + e)) & 63]);
    int js = (j & ~7) | ((j & 7) ^ (o & 7));
    *(u16x8*)(Wb + (((size_t)o) << 10) + (js << 3)) = v;
}

// ---------------- kernel 2: fused 128x128 GEMM ----------------
#define BAR() __builtin_amdgcn_s_barrier()
#define LGKM0() asm volatile("s_waitcnt lgkmcnt(0)" ::: "memory")
#define VMCNT(n) asm volatile("s_waitcnt vmcnt(" #n ")" ::: "memory")
#define CFENCE() asm volatile("" ::: "memory")
#define SETPRIO(n) __builtin_amdgcn_s_setprio(n)
#define MFMA4(d, av, bv) d = __builtin_amdgcn_mfma_f32_16x16x32_bf16(av, bv, d, 0, 0, 0)

// A half stage: half H (glob-row bit4), 2 planes x 8KB = 16 KB, 2 gload16/thread.
// Per-lane glob src carries the sigma-rotated, row-XOR'd granule; LDS dest linear.
#define STAGE_AH(buf, H, t) do {                                                 \
    const char* _s = srcA + (((size_t)(H)) << 16) + ((t) << 8);                  \
    char* _d = (buf) + (wv << 10);                                               \
    GLOAD16(_s,       _d);                                                       \
    GLOAD16(_s + 128, _d + 8192);                                                \
} while (0)

// B stage: 128 rows x 128 B = 16 KB, 2 gload16/thread (pre-swizzled Wb).
#define STAGE_B(buf, t) do {                                                     \
    const char* _s = srcB + ((t) << 7);                                          \
    char* _d = (buf) + (wv << 10);                                               \
    GLOAD16(_s, _d);                                                             \
    GLOAD16(_s + ((size_t)64 << 11), _d + 8192);                                 \
} while (0)

// A fragment read+cvt from half-buffer (4x ds_read_b128 fp32 -> 2 bf16x8)
#define AREAD(aF, buf) do {                                                      \
    f32x4 _l0 = *(const f32x4*)((buf) + a_rd[0][0]);                             \
    f32x4 _h0 = *(const f32x4*)((buf) + a_rd[0][1]);                             \
    f32x4 _l1 = *(const f32x4*)((buf) + a_rd[1][0]);                             \
    f32x4 _h1 = *(const f32x4*)((buf) + a_rd[1][1]);                             \
    aF[0] = cvt8(_l0, _h0);                                                      \
    aF[1] = cvt8(_l1, _h1);                                                      \
} while (0)

// One K-tile (2 phases), R10 schedule verbatim.
#define BODY(t, Bcur, Bnxt, LAST) do {                                           \
    bf16x8 aF0[2], aF1[2], bfr[4][2];                                            \
    AREAD(aF0, Ah0);                                                             \
    _Pragma("unroll") for (int n = 0; n < 4; ++n)                                \
      _Pragma("unroll") for (int ks = 0; ks < 2; ++ks)                           \
        bfr[n][ks] = *(const bf16x8*)((Bcur) + b_off[ks] + n * 2048);            \
    LGKM0(); BAR();                      /* all P1 reads done */                 \
    if (!(LAST)) { STAGE_AH(Ah0, 0, (t) + 1); STAGE_B(Bnxt, (t) + 1); }          \
    SETPRIO(1);                                                                  \
    _Pragma("unroll") for (int n = 0; n < 4; ++n) {                              \
        MFMA4(acc[0][n], aF0[0], bfr[n][0]);                                     \
        MFMA4(acc[0][n], aF0[1], bfr[n][1]);                                     \
    }                                                                            \
    SETPRIO(0);                                                                  \
    if (LAST) { VMCNT(0); } else { VMCNT(4); }   /* Ah1(t) landed */             \
    BAR();                                                                       \
    AREAD(aF1, Ah1);                                                             \
    LGKM0();                                                                     \
    SETPRIO(1);                                                                  \
    _Pragma("unroll") for (int n = 0; n < 4; ++n) {                              \
        MFMA4(acc[1][n], aF1[0], bfr[n][0]);                                     \
        MFMA4(acc[1][n], aF1[1], bfr[n][1]);                                     \
    }                                                                            \
    SETPRIO(0);                                                                  \
    if (!(LAST)) {                                                               \
        BAR();                           /* all P2 reads done */                 \
        STAGE_AH(Ah1, 1, (t) + 1);                                               \
        VMCNT(2);                        /* Ah0(t+1)+B(t+1) landed */            \
        BAR(); CFENCE();                                                         \
    }                                                                            \
} while (0)

__global__ void __launch_bounds__(512, 4) gemm_fused_kernel(const float* __restrict__ X,
                                                            const unsigned short* __restrict__ B,
                                                            float* __restrict__ C) {
    __shared__ __align__(16) char lds[65536];
    char* Ah0 = lds;                 // half0: planes ks0@0, ks1@8192; [64 rows][128B]
    char* Ah1 = lds + 16384;         // half1 (glob rows +16)
    char* Bs0 = lds + 32768;
    char* Bs1 = lds + 49152;

    int tid  = threadIdx.x;
    int lane = tid & 63;
    int wv   = tid >> 6;       // 0..7
    int wr   = wv >> 1;        // 0..3  (M: 4 x 32 rows)
    int wc   = wv & 1;         // 0..1  (N: 2 x 64 cols)

    // T1: XCD-chunked swizzle (2048 blocks, R4 verbatim)
    int cpx = gridDim.x >> 3;
    int wid = ((int)blockIdx.x & 7) * cpx + ((int)blockIdx.x >> 3);
    int tn = wid & 7, tm = wid >> 3;
    int m0 = tm * 128, n0 = tn * 128;

    // ---- A staging source ----
    // lds-row l6 = tid>>3 (0..63), phys granule g = tid&7.
    // glob row = m0 + (l6&15) + ((l6>>4)<<5)  [+16*H per instr]
    // logical granule = sigma(g ^ (l6&7)), sigma(x) = ((x&3)<<1)|(x>>2)
    // glob byte-in-row = t*256 + ks*128 + logical*16
    int l6 = tid >> 3;
    int gx = (tid & 7) ^ (l6 & 7);
    int lg = ((gx & 3) << 1) | (gx >> 2);
    int growA = (l6 & 15) | ((l6 >> 4) << 5);
    const char* srcA = (const char*)X + (((size_t)(m0 + growA)) << 12) + (lg << 4);

    // B staging source (pre-swizzled Wb -> linear gather, R4 verbatim)
    const char* srcB = (const char*)B + (((size_t)(n0 + (tid >> 3))) << 11) + ((tid & 7) << 4);

    // ---- A fragment read offsets ----
    // plane ks @ ks*8192; row l = wr*16 + (lane&15), stride 128 B (bit7 = row&1);
    // phys granule = (q | h<<2) ^ p  -> logical 2q+h.
    int p = lane & 7;
    int q = lane >> 4;
    int abase = (wr * 16 + (lane & 15)) * 128;
    int a_rd[2][2];
#pragma unroll
    for (int ks = 0; ks < 2; ++ks)
#pragma unroll
        for (int h = 0; h < 2; ++h)
            a_rd[ks][h] = ks * 8192 + abase + (((q | (h << 2)) ^ p) << 4);

    // B fragment read offsets (R2/R4 proven verbatim)
    int kq16 = q << 4;
    int bbase = (wc * 64 + (lane & 15)) * 128;
    int b_off[2] = { bbase + ((kq16 + 0)  ^ (p << 4)),
                     bbase + ((kq16 + 64) ^ (p << 4)) };

    f32x4 acc[2][4] = {};

    // ---- prologue: full tile 0 ----
    STAGE_AH(Ah0, 0, 0); STAGE_AH(Ah1, 1, 0); STAGE_B(Bs0, 0);
    VMCNT(0); BAR(); CFENCE();

    // ---- main loop ----
    for (int t = 0; t < NKT - 2; t += 2) {
        BODY(t,     Bs0, Bs1, false);
        BODY(t + 1, Bs1, Bs0, false);
    }
    BODY(NKT - 2, Bs0, Bs1, false);
    BODY(NKT - 1, Bs1, Bs0, true);

    // ---- epilogue: C/D layout col = lane&15, row = (lane>>4)*4 + j (proven) ----
    float* Cp = C + ((size_t)(m0 + wr * 32)) * NCH + n0 + wc * 64;
    int cc = lane & 15;
    int rr = (lane >> 4) << 2;
#pragma unroll
    for (int m = 0; m < 2; ++m)
#pragma unroll
        for (int j = 0; j < 4; ++j) {
            float* rowp = Cp + ((size_t)(m * 16 + rr + j)) * NCH;
#pragma unroll
            for (int n = 0; n < 4; ++n)
                rowp[n * 16 + cc] = acc[m][n][j];
        }
}

// ---------------- fallback (ws too small): naive fp32 ----------------
__global__ void naive_kernel(const float* __restrict__ x, const float* __restrict__ w,
                             float* __restrict__ out) {
    int t = blockIdx.x;
    int o = blockIdx.y * 256 + threadIdx.x;
    const float* xr = x + (size_t)t * NCH;
    int r = o >> 6, oi = o & 63;
    float s = 0.f;
    for (int qq = 0; qq < 16; ++qq) {
        const float* wq = w + (r * 16 + qq) * 64;
        const float* xq = xr + qq * 64;
#pragma unroll 8
        for (int j = 0; j < 64; ++j) s += xq[j] * wq[(oi - j) & 63];
    }
    out[(size_t)t * NCH + o] = s;
}

extern "C" void kernel_launch(void* const* d_in, const int* in_sizes, int n_in,
                              void* d_out, int out_size, void* d_ws, size_t ws_size,
                              hipStream_t stream) {
    const float* x = (const float*)d_in[0];
    const float* w = (const float*)d_in[1];
    float* out = (float*)d_out;

    const size_t needW = (size_t)NCH * NCH * sizeof(unsigned short);   // 2 MB

    if (ws_size >= needW) {
        unsigned short* Wb = (unsigned short*)d_ws;
        hipLaunchKernelGGL(build_w_kernel, dim3(NCH * 128 / 256), dim3(256), 0, stream, w, Wb);
        hipLaunchKernelGGL(gemm_fused_kernel, dim3(2048), dim3(512), 0, stream, x, Wb, out);
    } else {
        hipLaunchKernelGGL(naive_kernel, dim3(NTOK, 4), dim3(256), 0, stream, x, w, out);
    }
}